// Round 1
// baseline (59.413 us; speedup 1.0000x reference)
//
#include <hip/hip_runtime.h>

// MODWT (stationary wavelet, sym4, level 5, no filter upsampling in the
// reference) — outputs h4, h5, lowpass5 stacked as (B,1,3,T).
//
// Key identity: circular cross-correlation with pad=4 composes as plain
// convolution of the tap arrays. So:
//   h4[t]  = sum_m F4[m] * x[(t+m-16) mod T],  F4 = lo*lo*lo*hi  (29 taps)
//   h5[t]  = sum_m F5[m] * x[(t+m-20) mod T],  F5 = lo^4 * hi    (36 taps)
//   lo5[t] = sum_m FL[m] * x[(t+m-20) mod T],  FL = lo^5         (36 taps)
// One fused pass: read x once (67 MB), write 3 planes (201 MB).
// Filters are the fixed reference constants -> composed in constexpr double
// at compile time, emitted as FMA literals.

#define TILE 1024            // output points per block
#define NCHUNK ((TILE + 36) / 4)   // 265 float4 chunks staged in LDS

static constexpr float SYM4_LO[8] = {
    -0.07576571478927333f, -0.02963552764599851f, 0.49761866763201545f,
     0.8037387518059161f,   0.29785779560527736f, -0.09921954357684722f,
    -0.012603967262037833f, 0.032223100604071304f};
static constexpr float SYM4_HI[8] = {
    -0.032223100604071304f, -0.012603967262037833f, 0.09921954357684722f,
     0.29785779560527736f,  -0.8037387518059161f,   0.49761866763201545f,
     0.02963552764599851f,  -0.07576571478927333f};

struct FiltPack {
    float f4[36];  // h4 filter, padded to window [t-20, t+15] (zeros at m<4, m>32)
    float f5[36];  // h5 filter
    float fl[36];  // lowpass5 filter
};

constexpr FiltPack make_filters() {
    double lo[8], hi[8];
    for (int i = 0; i < 8; ++i) { lo[i] = SYM4_LO[i]; hi[i] = SYM4_HI[i]; }
    double l2[15] = {}, l3[22] = {}, l4[29] = {};
    for (int i = 0; i < 8;  ++i) for (int j = 0; j < 8; ++j) l2[i + j] += lo[i] * lo[j];
    for (int i = 0; i < 15; ++i) for (int j = 0; j < 8; ++j) l3[i + j] += l2[i] * lo[j];
    for (int i = 0; i < 22; ++i) for (int j = 0; j < 8; ++j) l4[i + j] += l3[i] * lo[j];
    double f4[29] = {}, f5[36] = {}, fl[36] = {};
    for (int i = 0; i < 22; ++i) for (int j = 0; j < 8; ++j) f4[i + j] += l3[i] * hi[j];
    for (int i = 0; i < 29; ++i) for (int j = 0; j < 8; ++j) f5[i + j] += l4[i] * hi[j];
    for (int i = 0; i < 29; ++i) for (int j = 0; j < 8; ++j) fl[i + j] += l4[i] * lo[j];
    FiltPack r = {};
    for (int m = 0; m < 36; ++m) {
        r.f4[m] = (m >= 4 && m < 33) ? (float)f4[m - 4] : 0.0f;
        r.f5[m] = (float)f5[m];
        r.fl[m] = (float)fl[m];
    }
    return r;
}
static constexpr FiltPack FP = make_filters();

__global__ __launch_bounds__(256)
void modwt_fused_kernel(const float* __restrict__ x, float* __restrict__ out, int Tn) {
    const int T4  = Tn >> 2;                  // float4 chunks per row
    const int b   = blockIdx.y;               // batch row
    const int bs4 = blockIdx.x * (TILE / 4);  // tile start, in float4 chunks

    __shared__ float4 s4[NCHUNK];             // s4[c] = x[bs - 20 + 4c .. +3] (wrapped)

    const float4* x4 = reinterpret_cast<const float4*>(x) + (size_t)b * T4;
    for (int i = threadIdx.x; i < NCHUNK; i += 256) {
        int g = bs4 - 5 + i;                  // -20 floats = -5 chunks
        if (g < 0)    g += T4;                // circular wrap (range is [-5, T4+260))
        if (g >= T4)  g -= T4;
        s4[i] = x4[g];
    }
    __syncthreads();

    // Each thread computes 4 consecutive outputs: t0 = bs + 4*tid.
    // Window floats needed: s_x[4*tid .. 4*tid+38] -> chunks tid .. tid+9.
    float w[40];
    #pragma unroll
    for (int j = 0; j < 10; ++j)
        reinterpret_cast<float4*>(w)[j] = s4[threadIdx.x + j];

    float a4[4] = {0.f, 0.f, 0.f, 0.f};
    float a5[4] = {0.f, 0.f, 0.f, 0.f};
    float al[4] = {0.f, 0.f, 0.f, 0.f};
    #pragma unroll
    for (int m = 0; m < 36; ++m) {
        const float c4 = FP.f4[m];
        const float c5 = FP.f5[m];
        const float cl = FP.fl[m];
        #pragma unroll
        for (int j = 0; j < 4; ++j) {
            const float xv = w[m + j];
            a4[j] = fmaf(c4, xv, a4[j]);
            a5[j] = fmaf(c5, xv, a5[j]);
            al[j] = fmaf(cl, xv, al[j]);
        }
    }

    // out shape (B,1,3,T): plane s at ((b*3+s)*T). Coalesced float4 stores.
    float4* o4 = reinterpret_cast<float4*>(out);
    const size_t base = (size_t)b * 3 * T4 + bs4 + threadIdx.x;
    o4[base]                 = make_float4(a4[0], a4[1], a4[2], a4[3]);
    o4[base + T4]            = make_float4(a5[0], a5[1], a5[2], a5[3]);
    o4[base + 2 * (size_t)T4] = make_float4(al[0], al[1], al[2], al[3]);
}

extern "C" void kernel_launch(void* const* d_in, const int* in_sizes, int n_in,
                              void* d_out, int out_size, void* d_ws, size_t ws_size,
                              hipStream_t stream) {
    const float* x = (const float*)d_in[0];
    float* out = (float*)d_out;
    const int B  = 16;
    const int Tn = in_sizes[0] / B;           // 1048576

    dim3 grid(Tn / TILE, B);
    dim3 block(256);
    modwt_fused_kernel<<<grid, block, 0, stream>>>(x, out, Tn);
}

// Round 3
// 52.792 us; speedup vs baseline: 1.1254x; 1.1254x over previous
//
#include <hip/hip_runtime.h>

// MODWT (sym4, level 5, no à-trous upsampling) — outputs h4, h5, lowpass5 as (B,1,3,T).
//
// Circular cross-correlations compose: each output is ONE circular FIR of x.
//   h4[t]  = sum_m F4[m] x[(t+m-16) mod T],  F4 = lo*lo*lo*hi  (29 taps)
//   h5[t]  = sum_m F5[m] x[(t+m-20) mod T],  F5 = lo^4 * hi    (36 taps)
//   lo5[t] = sum_m FL[m] x[(t+m-20) mod T],  FL = lo^5         (36 taps)
// Round 3: same as round 2 (persistent blocks, register-staged 2-phase
// pipeline, nontemporal stores, zero-tap skip) with the nontemporal-store
// compile fix: use clang ext_vector float4 (native vector) instead of
// HIP_vector_type, which the builtin rejects.

#define TILE      1024        // output points per tile
#define NCHUNK    265         // float4 chunks staged per tile (TILE/4 + 9 halo)
#define TPB_TILES 8           // tiles processed per block

typedef float f4v __attribute__((ext_vector_type(4)));  // native vector float4

static constexpr float SYM4_LO[8] = {
    -0.07576571478927333f, -0.02963552764599851f, 0.49761866763201545f,
     0.8037387518059161f,   0.29785779560527736f, -0.09921954357684722f,
    -0.012603967262037833f, 0.032223100604071304f};
static constexpr float SYM4_HI[8] = {
    -0.032223100604071304f, -0.012603967262037833f, 0.09921954357684722f,
     0.29785779560527736f,  -0.8037387518059161f,   0.49761866763201545f,
     0.02963552764599851f,  -0.07576571478927333f};

struct FiltPack {
    float f4[36];  // h4 filter padded to window [t-20, t+15] (zeros m<4, m>32)
    float f5[36];
    float fl[36];
};

constexpr FiltPack make_filters() {
    double lo[8], hi[8];
    for (int i = 0; i < 8; ++i) { lo[i] = SYM4_LO[i]; hi[i] = SYM4_HI[i]; }
    double l2[15] = {}, l3[22] = {}, l4[29] = {};
    for (int i = 0; i < 8;  ++i) for (int j = 0; j < 8; ++j) l2[i + j] += lo[i] * lo[j];
    for (int i = 0; i < 15; ++i) for (int j = 0; j < 8; ++j) l3[i + j] += l2[i] * lo[j];
    for (int i = 0; i < 22; ++i) for (int j = 0; j < 8; ++j) l4[i + j] += l3[i] * lo[j];
    double f4[29] = {}, f5[36] = {}, fl[36] = {};
    for (int i = 0; i < 22; ++i) for (int j = 0; j < 8; ++j) f4[i + j] += l3[i] * hi[j];
    for (int i = 0; i < 29; ++i) for (int j = 0; j < 8; ++j) f5[i + j] += l4[i] * hi[j];
    for (int i = 0; i < 29; ++i) for (int j = 0; j < 8; ++j) fl[i + j] += l4[i] * lo[j];
    FiltPack r = {};
    for (int m = 0; m < 36; ++m) {
        r.f4[m] = (m >= 4 && m < 33) ? (float)f4[m - 4] : 0.0f;
        r.f5[m] = (float)f5[m];
        r.fl[m] = (float)fl[m];
    }
    return r;
}
static constexpr FiltPack FP = make_filters();

__global__ __launch_bounds__(256)
void modwt_fused_kernel(const float* __restrict__ x, float* __restrict__ out,
                        int Tn, int tilesPerRow, int totalTiles) {
    const int T4  = Tn >> 2;
    const int tid = threadIdx.x;
    const bool have2 = (tid < NCHUNK - 256);   // 9 threads load a second chunk

    __shared__ f4v s4[NCHUNK];                 // s4[c] = x[bs-20+4c ..+3] (wrapped)

    const f4v* xbase = reinterpret_cast<const f4v*>(x);
    f4v* o4 = reinterpret_cast<f4v*>(out);

    int tile = blockIdx.x;

    // Prologue: stage tile 0 into registers.
    f4v c0, c1;
    {
        const int b   = tile / tilesPerRow;
        const int bs4 = (tile % tilesPerRow) * (TILE / 4);
        const f4v* xr = xbase + (size_t)b * T4;
        int g0 = bs4 - 5 + tid;           if (g0 < 0)   g0 += T4;
        c0 = xr[g0];
        if (have2) { int g1 = bs4 - 5 + 256 + tid; if (g1 >= T4) g1 -= T4; c1 = xr[g1]; }
    }

    for (int k = 0; k < TPB_TILES; ++k) {
        const int b   = tile / tilesPerRow;
        const int bs4 = (tile % tilesPerRow) * (TILE / 4);

        __syncthreads();                   // previous tile's readers of s4 done
        s4[tid] = c0;
        if (have2) s4[256 + tid] = c1;

        // Issue NEXT tile's staging loads now; they complete under this
        // tile's compute (latency hidden; waitcnt lands before next ds_write).
        const int ntile = tile + gridDim.x;
        if (ntile < totalTiles) {
            const int nb   = ntile / tilesPerRow;
            const int nbs4 = (ntile % tilesPerRow) * (TILE / 4);
            const f4v* xr = xbase + (size_t)nb * T4;
            int g0 = nbs4 - 5 + tid;          if (g0 < 0)   g0 += T4;
            c0 = xr[g0];
            if (have2) { int g1 = nbs4 - 5 + 256 + tid; if (g1 >= T4) g1 -= T4; c1 = xr[g1]; }
        }
        __syncthreads();                   // s4 ready

        // Window: outputs t0 = bs + 4*tid .. +3, floats s[4*tid .. 4*tid+38].
        float w[40];
        #pragma unroll
        for (int j = 0; j < 10; ++j)
            reinterpret_cast<f4v*>(w)[j] = s4[tid + j];

        float a4[4] = {0.f, 0.f, 0.f, 0.f};
        float a5[4] = {0.f, 0.f, 0.f, 0.f};
        float al[4] = {0.f, 0.f, 0.f, 0.f};
        #pragma unroll
        for (int m = 0; m < 36; ++m) {
            const float c4v = FP.f4[m];    // constexpr -> folded; zero taps skipped
            const float c5v = FP.f5[m];
            const float clv = FP.fl[m];
            #pragma unroll
            for (int j = 0; j < 4; ++j) {
                const float xv = w[m + j];
                if (c4v != 0.0f) a4[j] = fmaf(c4v, xv, a4[j]);
                a5[j] = fmaf(c5v, xv, a5[j]);
                al[j] = fmaf(clv, xv, al[j]);
            }
        }

        // out (B,1,3,T): plane s at (b*3+s)*T. Streaming -> nontemporal.
        const size_t base = ((size_t)b * 3) * T4 + bs4 + tid;
        f4v v4 = {a4[0], a4[1], a4[2], a4[3]};
        f4v v5 = {a5[0], a5[1], a5[2], a5[3]};
        f4v vl = {al[0], al[1], al[2], al[3]};
        __builtin_nontemporal_store(v4, &o4[base]);
        __builtin_nontemporal_store(v5, &o4[base + T4]);
        __builtin_nontemporal_store(vl, &o4[base + 2 * (size_t)T4]);

        tile = ntile;
    }
}

extern "C" void kernel_launch(void* const* d_in, const int* in_sizes, int n_in,
                              void* d_out, int out_size, void* d_ws, size_t ws_size,
                              hipStream_t stream) {
    const float* x = (const float*)d_in[0];
    float* out = (float*)d_out;
    const int B  = 16;
    const int Tn = in_sizes[0] / B;            // 1048576
    const int tilesPerRow = Tn / TILE;         // 1024
    const int totalTiles  = B * tilesPerRow;   // 16384

    dim3 grid(totalTiles / TPB_TILES);         // 2048 persistent blocks
    dim3 block(256);
    modwt_fused_kernel<<<grid, block, 0, stream>>>(x, out, Tn, tilesPerRow, totalTiles);
}

// Round 4
// 51.173 us; speedup vs baseline: 1.1610x; 1.0316x over previous
//
#include <hip/hip_runtime.h>

// MODWT (sym4, level 5, no à-trous upsampling) — outputs h4, h5, lowpass5 as (B,1,3,T).
//
// Circular cross-correlations compose: each output is ONE circular FIR of x.
//   h4[t]  = sum_m F4[m] x[(t+m-16) mod T],  F4 = lo*lo*lo*hi  (29 taps)
//   h5[t]  = sum_m F5[m] x[(t+m-20) mod T],  F5 = lo^4 * hi    (36 taps)
//   lo5[t] = sum_m FL[m] x[(t+m-20) mod T],  FL = lo^5         (36 taps)
//
// Round 4: NO LDS, NO barriers. Round 3 showed 5.1 TB/s vs ~6.9 achievable;
// theory: the per-tile __syncthreads (s_waitcnt vmcnt(0)) serially drained
// nontemporal-store latency every tile. Here each thread loads its 40-float
// window directly (10 global_load_dwordx4 off one base pointer; overlap served
// by L1 — HBM fetch stays ~67 MB), computes 4 outputs x 3 planes, and fires
// 3 nontemporal stores with no waits at all. Waves retire independently.

typedef float f4v __attribute__((ext_vector_type(4)));

static constexpr float SYM4_LO[8] = {
    -0.07576571478927333f, -0.02963552764599851f, 0.49761866763201545f,
     0.8037387518059161f,   0.29785779560527736f, -0.09921954357684722f,
    -0.012603967262037833f, 0.032223100604071304f};
static constexpr float SYM4_HI[8] = {
    -0.032223100604071304f, -0.012603967262037833f, 0.09921954357684722f,
     0.29785779560527736f,  -0.8037387518059161f,   0.49761866763201545f,
     0.02963552764599851f,  -0.07576571478927333f};

struct FiltPack {
    float f4[36];  // h4 filter padded to window [t-20, t+15] (zeros m<4, m>32)
    float f5[36];
    float fl[36];
};

constexpr FiltPack make_filters() {
    double lo[8], hi[8];
    for (int i = 0; i < 8; ++i) { lo[i] = SYM4_LO[i]; hi[i] = SYM4_HI[i]; }
    double l2[15] = {}, l3[22] = {}, l4[29] = {};
    for (int i = 0; i < 8;  ++i) for (int j = 0; j < 8; ++j) l2[i + j] += lo[i] * lo[j];
    for (int i = 0; i < 15; ++i) for (int j = 0; j < 8; ++j) l3[i + j] += l2[i] * lo[j];
    for (int i = 0; i < 22; ++i) for (int j = 0; j < 8; ++j) l4[i + j] += l3[i] * lo[j];
    double f4[29] = {}, f5[36] = {}, fl[36] = {};
    for (int i = 0; i < 22; ++i) for (int j = 0; j < 8; ++j) f4[i + j] += l3[i] * hi[j];
    for (int i = 0; i < 29; ++i) for (int j = 0; j < 8; ++j) f5[i + j] += l4[i] * hi[j];
    for (int i = 0; i < 29; ++i) for (int j = 0; j < 8; ++j) fl[i + j] += l4[i] * lo[j];
    FiltPack r = {};
    for (int m = 0; m < 36; ++m) {
        r.f4[m] = (m >= 4 && m < 33) ? (float)f4[m - 4] : 0.0f;
        r.f5[m] = (float)f5[m];
        r.fl[m] = (float)fl[m];
    }
    return r;
}
static constexpr FiltPack FP = make_filters();

__global__ __launch_bounds__(256)
void modwt_direct_kernel(const float* __restrict__ x, float* __restrict__ out, int Tn) {
    const int T4 = Tn >> 2;                               // float4 chunks per row
    const int g  = blockIdx.x * 256 + threadIdx.x;        // global output-quad id
    const int b  = g / T4;                                // batch row
    const int c  = g - b * T4;                            // chunk within row
    // Outputs t0..t0+3, t0 = 4c. Window floats [t0-20, t0+19] = chunks c-5..c+4.

    const f4v* xr = reinterpret_cast<const f4v*>(x) + (size_t)b * T4;

    float w[40];
    if (c >= 5 && c + 5 <= T4) {
        // Fast path: one base pointer, 10 loads with immediate offsets.
        const f4v* p = xr + (c - 5);
        #pragma unroll
        for (int j = 0; j < 10; ++j)
            reinterpret_cast<f4v*>(w)[j] = p[j];
    } else {
        #pragma unroll
        for (int j = 0; j < 10; ++j) {
            int gc = c - 5 + j;
            if (gc < 0)    gc += T4;
            if (gc >= T4)  gc -= T4;
            reinterpret_cast<f4v*>(w)[j] = xr[gc];
        }
    }

    float a4[4] = {0.f, 0.f, 0.f, 0.f};
    float a5[4] = {0.f, 0.f, 0.f, 0.f};
    float al[4] = {0.f, 0.f, 0.f, 0.f};
    #pragma unroll
    for (int m = 0; m < 36; ++m) {
        const float c4v = FP.f4[m];   // constexpr -> folded; zero taps skipped
        const float c5v = FP.f5[m];
        const float clv = FP.fl[m];
        #pragma unroll
        for (int j = 0; j < 4; ++j) {
            const float xv = w[m + j];
            if (c4v != 0.0f) a4[j] = fmaf(c4v, xv, a4[j]);
            a5[j] = fmaf(c5v, xv, a5[j]);
            al[j] = fmaf(clv, xv, al[j]);
        }
    }

    // out (B,1,3,T): plane s at (b*3+s)*T. Streaming -> nontemporal, no waits.
    f4v* o4 = reinterpret_cast<f4v*>(out);
    const size_t base = ((size_t)b * 3) * T4 + c;
    f4v v4 = {a4[0], a4[1], a4[2], a4[3]};
    f4v v5 = {a5[0], a5[1], a5[2], a5[3]};
    f4v vl = {al[0], al[1], al[2], al[3]};
    __builtin_nontemporal_store(v4, &o4[base]);
    __builtin_nontemporal_store(v5, &o4[base + T4]);
    __builtin_nontemporal_store(vl, &o4[base + 2 * (size_t)T4]);
}

extern "C" void kernel_launch(void* const* d_in, const int* in_sizes, int n_in,
                              void* d_out, int out_size, void* d_ws, size_t ws_size,
                              hipStream_t stream) {
    const float* x = (const float*)d_in[0];
    float* out = (float*)d_out;
    const int B  = 16;
    const int Tn = in_sizes[0] / B;            // 1048576
    const int totalQuads = B * (Tn / 4);       // 4,194,304 output-quads

    dim3 grid(totalQuads / 256);               // 16384 blocks
    dim3 block(256);
    modwt_direct_kernel<<<grid, block, 0, stream>>>(x, out, Tn);
}